// Round 7
// baseline (191.341 us; speedup 1.0000x reference)
//
#include <hip/hip_runtime.h>

typedef int   v4i __attribute__((ext_vector_type(4)));
typedef float v4f __attribute__((ext_vector_type(4)));

#define N_ROWS   262144
#define IN_F     256
#define OUT_F    256
#define N_TILES  (N_ROWS / 16)      // 16384

// ---------------- prep: weight int32 -> int8, per-channel offset & scale ----
__global__ void qlin_prep(const int* __restrict__ w,
                          const int* __restrict__ bias,
                          const float* __restrict__ is,
                          const float* __restrict__ wsc,
                          const float* __restrict__ os,
                          const int* __restrict__ izp,
                          signed char* __restrict__ w8,
                          int* __restrict__ off,
                          float* __restrict__ scale) {
    int o = blockIdx.x;
    int k = threadIdx.x;
    int v = w[o * IN_F + k];
    w8[o * IN_F + k] = (signed char)v;
    __shared__ int red[256];
    red[k] = v;
    __syncthreads();
    for (int s = 128; s > 0; s >>= 1) {
        if (k < s) red[k] += red[k + s];
        __syncthreads();
    }
    if (k == 0) {
        off[o]   = bias[o] - izp[0] * red[0];
        scale[o] = is[0] * wsc[o] / os[0];
    }
}

// ---------------- main GEMM: one 16-row tile per block (churn) --------------
__device__ inline int pack4(v4i a) {
    return (a.x & 255) | ((a.y & 255) << 8) | ((a.z & 255) << 16) | (a.w & 255 ? (a.w << 24) : (a.w << 24));
}

#define WAIT_VM(n) asm volatile("s_waitcnt vmcnt(" #n ")" ::: "memory")
#define BAR()  __builtin_amdgcn_s_barrier()

__global__ __launch_bounds__(256, 2) void
qlin_main(const int* __restrict__ x,           // [N][256] int32
          const signed char* __restrict__ w8,  // [256][256] int8
          const int* __restrict__ off,         // [256]
          const float* __restrict__ scale,     // [256]
          const int* __restrict__ ozp,         // [1]
          int* __restrict__ out) {             // [N][256] int32 (int8 values)
    __shared__ int lbuf[4096];                 // one 16 KB x-tile

    const int tid  = threadIdx.x;
    const int wid  = tid >> 6;
    const int lane = tid & 63;
    const int l15  = lane & 15;
    const int lg   = lane >> 4;
    const int chBase = wid * 64;

    // ---- stage this block's x-tile FIRST (HBM latency shadow) --------------
    // LDS dest linear, XOR swizzle applied on the GLOBAL source (rule #21).
    {
        const char* base = (const char*)x + (size_t)blockIdx.x * (16 * IN_F * 4);
#pragma unroll
        for (int j = 0; j < 4; ++j) {
            const int c = wid * 4 + j;             // chunk = tile row (1 KB)
            const int m = (c & 7) << 4;
            const char* src = base + c * 1024 + ((lane * 16) ^ m);
            __builtin_amdgcn_global_load_lds(
                (const __attribute__((address_space(1))) unsigned int*)src,
                (__attribute__((address_space(3))) unsigned int*)&lbuf[c * 256],
                16, 0, 0);
        }
    }

    // ---- weight fragments + per-channel constants (L2-resident, hidden) ----
    v4i Wf[4][4];
#pragma unroll
    for (int cf = 0; cf < 4; ++cf) {
        const signed char* wrow = w8 + (chBase + cf * 16 + l15) * IN_F + lg * 16;
#pragma unroll
        for (int kc = 0; kc < 4; ++kc)
            Wf[cf][kc] = *(const v4i*)(wrow + kc * 64);
    }
    v4i of4[4]; v4f sc4[4];
#pragma unroll
    for (int cf = 0; cf < 4; ++cf) {
        const int cb = chBase + cf * 16 + lg * 4;
        of4[cf] = *(const v4i*)(off + cb);
        sc4[cf] = *(const v4f*)(scale + cb);
    }
    const float ozpf = (float)ozp[0];

    // ---- wait for DMA + weights, one barrier ------------------------------
    WAIT_VM(0);
    BAR();

    // ---- compute: swizzled LDS reads -> pack -> MFMA ----------------------
    const int msk = (l15 & 7) << 4;
    const char* lp = (const char*)lbuf + l15 * 1024;
    v4i Xf[4];
#pragma unroll
    for (int kc = 0; kc < 4; ++kc) {
        v4i a0 = *(const v4i*)(lp + kc * 256 + ((lg * 64 +  0) ^ msk));
        v4i a1 = *(const v4i*)(lp + kc * 256 + ((lg * 64 + 16) ^ msk));
        v4i a2 = *(const v4i*)(lp + kc * 256 + ((lg * 64 + 32) ^ msk));
        v4i a3 = *(const v4i*)(lp + kc * 256 + ((lg * 64 + 48) ^ msk));
        v4i pk;
        pk.x = (a0.x & 255) | ((a0.y & 255) << 8) | ((a0.z & 255) << 16) | (a0.w << 24);
        pk.y = (a1.x & 255) | ((a1.y & 255) << 8) | ((a1.z & 255) << 16) | (a1.w << 24);
        pk.z = (a2.x & 255) | ((a2.y & 255) << 8) | ((a2.z & 255) << 16) | (a2.w << 24);
        pk.w = (a3.x & 255) | ((a3.y & 255) << 8) | ((a3.z & 255) << 16) | (a3.w << 24);
        Xf[kc] = pk;
    }

    v4i acc[4];
#pragma unroll
    for (int cf = 0; cf < 4; ++cf) acc[cf] = (v4i){0, 0, 0, 0};
#pragma unroll
    for (int kc = 0; kc < 4; ++kc)
#pragma unroll
        for (int cf = 0; cf < 4; ++cf)
            acc[cf] = __builtin_amdgcn_mfma_i32_16x16x64_i8(Wf[cf][kc], Xf[kc], acc[cf], 0, 0, 0);

    // ---- epilogue + coalesced stores --------------------------------------
    const int orow = (blockIdx.x * 16 + l15) * OUT_F + chBase + lg * 4;
#pragma unroll
    for (int cf = 0; cf < 4; ++cf) {
        v4i res;
#pragma unroll
        for (int r = 0; r < 4; ++r) {
            float v = (float)(acc[cf][r] + of4[cf][r]) * sc4[cf][r] + ozpf;
            v = rintf(v);
            v = fminf(fmaxf(v, -128.0f), 127.0f);
            res[r] = (int)v;
        }
        *(v4i*)(out + orow + cf * 16) = res;
    }
}

extern "C" void kernel_launch(void* const* d_in, const int* in_sizes, int n_in,
                              void* d_out, int out_size, void* d_ws, size_t ws_size,
                              hipStream_t stream) {
    const int*   x   = (const int*)d_in[0];
    const int*   w   = (const int*)d_in[1];
    const int*   b   = (const int*)d_in[2];
    const float* is  = (const float*)d_in[3];
    const float* wsc = (const float*)d_in[4];
    const float* os  = (const float*)d_in[5];
    const int*   izp = (const int*)d_in[6];
    const int*   ozp = (const int*)d_in[7];
    int* out = (int*)d_out;

    signed char* w8    = (signed char*)d_ws;                 // 65536 B
    int*         off   = (int*)((char*)d_ws + 65536);        // 1024 B
    float*       scale = (float*)((char*)d_ws + 66560);      // 1024 B

    qlin_prep<<<256, 256, 0, stream>>>(w, b, is, wsc, os, izp, w8, off, scale);
    qlin_main<<<N_TILES, 256, 0, stream>>>(x, w8, off, scale, ozp, out);
}